// Round 1
// 1244.542 us; speedup vs baseline: 1.0239x; 1.0239x over previous
//
#include <hip/hip_runtime.h>
#include <cstdint>
#include <cstddef>

#define DIM 512
#define BM 128
#define BN 128
#define BK 32

typedef unsigned short ushort_t;
typedef __attribute__((ext_vector_type(8))) short short8;   // 8 bf16 MFMA frag
typedef __attribute__((ext_vector_type(4))) float floatx4;  // MFMA accumulator
typedef __attribute__((address_space(3))) void lds_void;
typedef __attribute__((address_space(1))) void gbl_void;

__device__ __forceinline__ float bf2f(ushort_t s) {
    unsigned u = ((unsigned)s) << 16;
    float f;
    __builtin_memcpy(&f, &u, 4);
    return f;
}
__device__ __forceinline__ ushort_t f2bf(float f) {  // round-to-nearest-even
    unsigned u;
    __builtin_memcpy(&u, &f, 4);
    u = u + 0x7FFFu + ((u >> 16) & 1u);
    return (ushort_t)(u >> 16);
}
__device__ __forceinline__ float elu_f(float x) { return x > 0.0f ? x : __expf(x) - 1.0f; }

// ---------------------------------------------------------------------------
// Dtype probe. flags[0]=1 if x is float32 (else bf16). flags[1]=1 if edges are
// int64 (else int32). f32 data read as bf16: even ushorts are mid-mantissa
// bits -> random exponent fields -> "crazy" bf16 values ~75% of the time.
// int64 edges in [-1,N): odd int32 words are sign-extensions (0 or -1) always.
// ---------------------------------------------------------------------------
__global__ void probe_kernel(const void* __restrict__ x, const void* __restrict__ e,
                             int* __restrict__ flags) {
    if (threadIdx.x != 0 || blockIdx.x != 0) return;
    const ushort_t* u = (const ushort_t*)x;
    int crazy = 0;
    for (int j = 0; j < 512; ++j) {
        const ushort_t s = u[2 * j];
        const int ex = (s >> 7) & 0xFF;
        const bool nonzero = (s & 0x7FFF) != 0;
        if (ex >= 160 || (ex < 96 && nonzero)) crazy++;
    }
    const int* w = (const int*)e;
    int se = 0;
    for (int j = 0; j < 64; ++j) {
        const int v = w[2 * j + 1];
        if (v == 0 || v == -1) se++;
    }
    flags[0] = (crazy > 64) ? 1 : 0;
    flags[1] = (se >= 60) ? 1 : 0;
}

// bias -> f32, either source dtype
__global__ void tof32_kernel(const void* __restrict__ src, float* __restrict__ dst,
                             int n, const int* __restrict__ flags) {
    const int i = blockIdx.x * blockDim.x + threadIdx.x;
    if (i < n) dst[i] = flags[0] ? ((const float*)src)[i] : bf2f(((const ushort_t*)src)[i]);
}

// ---------------------------------------------------------------------------
// src (f32 or bf16 per flag) -> hi bf16 (+ optional lo bf16 residual).
// 8 elements per thread, n must be a multiple of 8.
// ---------------------------------------------------------------------------
__global__ __launch_bounds__(256)
void split_kernel(const void* __restrict__ src, ushort_t* __restrict__ hi,
                  ushort_t* __restrict__ lo, long long n, const int* __restrict__ flags) {
    const long long i = ((long long)blockIdx.x * blockDim.x + threadIdx.x) * 8;
    if (i >= n) return;
    const bool isf32 = flags[0] != 0;
    float v[8];
    if (isf32) {
        const float* s = (const float*)src + i;
        const float4 f0 = *(const float4*)s;
        const float4 f1 = *(const float4*)(s + 4);
        v[0] = f0.x; v[1] = f0.y; v[2] = f0.z; v[3] = f0.w;
        v[4] = f1.x; v[5] = f1.y; v[6] = f1.z; v[7] = f1.w;
    } else {
        const ushort_t* s = (const ushort_t*)src + i;
        const ushort4 u0 = *(const ushort4*)s;
        const ushort4 u1 = *(const ushort4*)(s + 4);
        v[0] = bf2f(u0.x); v[1] = bf2f(u0.y); v[2] = bf2f(u0.z); v[3] = bf2f(u0.w);
        v[4] = bf2f(u1.x); v[5] = bf2f(u1.y); v[6] = bf2f(u1.z); v[7] = bf2f(u1.w);
    }
    ushort_t h[8];
    #pragma unroll
    for (int j = 0; j < 8; ++j) h[j] = f2bf(v[j]);
    ushort4 a, b;
    a.x = h[0]; a.y = h[1]; a.z = h[2]; a.w = h[3];
    b.x = h[4]; b.y = h[5]; b.z = h[6]; b.w = h[7];
    *(ushort4*)(hi + i) = a;
    *(ushort4*)(hi + i + 4) = b;
    if (lo) {
        ushort4 la, lb;
        la.x = isf32 ? f2bf(v[0] - bf2f(h[0])) : 0;
        la.y = isf32 ? f2bf(v[1] - bf2f(h[1])) : 0;
        la.z = isf32 ? f2bf(v[2] - bf2f(h[2])) : 0;
        la.w = isf32 ? f2bf(v[3] - bf2f(h[3])) : 0;
        lb.x = isf32 ? f2bf(v[4] - bf2f(h[4])) : 0;
        lb.y = isf32 ? f2bf(v[5] - bf2f(h[5])) : 0;
        lb.z = isf32 ? f2bf(v[6] - bf2f(h[6])) : 0;
        lb.w = isf32 ? f2bf(v[7] - bf2f(h[7])) : 0;
        *(ushort4*)(lo + i) = la;
        *(ushort4*)(lo + i + 4) = lb;
    }
}

__global__ void degree_kernel(const int* __restrict__ E, float* __restrict__ rdeg,
                              int n, const int* __restrict__ flags) {
    const int i = blockIdx.x * blockDim.x + threadIdx.x;
    if (i >= n) return;
    int e0, e1, e2;
    if (flags[1]) { e0 = E[i * 6 + 0]; e1 = E[i * 6 + 2]; e2 = E[i * 6 + 4]; }
    else          { e0 = E[i * 3 + 0]; e1 = E[i * 3 + 1]; e2 = E[i * 3 + 2]; }
    const int dg = 1 + (e0 >= 0) + (e1 >= 0) + (e2 >= 0);
    rdeg[i] = 1.0f / sqrtf((float)dg);
}

// ---------------------------------------------------------------------------
// H[row][col] = (sum_k A[row][k]*W[col][k] + bias[col]) * rdeg[row]
// with A ~ Ahi + Alo, W ~ Whi + Wlo (bf16 splits of f32), dropping lo*lo.
// 128x128 tile, BK=32, 4 waves. LDS [buf][tile][kb][row][8]: global_load_lds
// wave-uniform base + lane*16, conflict-free ds_read_b128.
//
// v2: T3-style 2-phase pipeline — double-buffered LDS, prefetch tile t+1
// before computing tile t, counted s_waitcnt vmcnt(CPW) (never 0 in the main
// loop) + raw s_barrier instead of __syncthreads' vmcnt(0) drain. Plus
// bijective XCD-aware block swizzle (4 N-blocks sharing an A-panel land on
// the same XCD's L2).
// ---------------------------------------------------------------------------
template <bool ALO, bool WLO, typename HT>
__global__ __launch_bounds__(256)
void gemm_gcn(const ushort_t* __restrict__ Ahi, const ushort_t* __restrict__ Alo,
              const ushort_t* __restrict__ Whi, const ushort_t* __restrict__ Wlo,
              const float* __restrict__ bias, const float* __restrict__ rdeg,
              HT* __restrict__ H, int M)
{
    constexpr int NTA = ALO ? 2 : 1;
    constexpr int NTW = WLO ? 2 : 1;
    constexpr int CPW = 2 * (NTA + NTW);  // 1KB staging chunks per wave per tile
    constexpr int NXB = DIM / BN;         // 4 N-blocks
    constexpr int NT  = DIM / BK;         // 16 K-tiles
    __shared__ __align__(16) ushort_t As[2][NTA][BK / 8][BM][8];
    __shared__ __align__(16) ushort_t Ws[2][NTW][BK / 8][BN][8];

    const int tid  = threadIdx.x;
    const int wave = tid >> 6;
    const int lane = tid & 63;

    // bijective XCD swizzle (m204): consecutive original ids (which share an
    // A-panel, since N is the fast grid dim) map to the same XCD.
    const int nwg = NXB * gridDim.y;
    const int bid = blockIdx.y * NXB + blockIdx.x;
    const int q = nwg >> 3, rm = nwg & 7;
    const int xcd = bid & 7, lin = bid >> 3;
    const int swz = (xcd < rm ? xcd * (q + 1) : rm * (q + 1) + (xcd - rm) * q) + lin;
    const int n_blk = (swz & (NXB - 1)) * BN;
    const int m_blk = (swz / NXB) * BM;

    const int m_off = (wave & 1) * 64;
    const int n_off = (wave >> 1) * 64;

    floatx4 acc[4][4] = {};

    auto stage = [&](int buf, int t) {
        const int k0 = t * BK;
        #pragma unroll
        for (int i = 0; i < CPW; ++i) {
            const int cc   = wave + i * 4;
            const int tile = cc >> 3;
            const int c    = cc & 7;
            const int kb   = c >> 1;
            const int rh   = (c & 1) * 64;
            if (tile < NTA) {
                int r = m_blk + rh + lane;
                r = r < M ? r : M - 1;  // clamp; rows >= M never stored
                const ushort_t* src = (tile == 0 ? Ahi : Alo) + (size_t)r * DIM + k0 + kb * 8;
                __builtin_amdgcn_global_load_lds((gbl_void*)src, (lds_void*)&As[buf][tile][kb][rh][0], 16, 0, 0);
            } else {
                const int tt = tile - NTA;
                const int r = n_blk + rh + lane;  // < 512 always
                const ushort_t* src = (tt == 0 ? Whi : Wlo) + (size_t)r * DIM + k0 + kb * 8;
                __builtin_amdgcn_global_load_lds((gbl_void*)src, (lds_void*)&Ws[buf][tt][kb][rh][0], 16, 0, 0);
            }
        }
    };

    auto compute = [&](int buf) {
        const int kbb = lane >> 4;  // lane quarter picks 8-wide K slice of K=32
        short8 ah[4], al[4], wh[4], wl[4];
        #pragma unroll
        for (int mi = 0; mi < 4; ++mi) {
            ah[mi] = *(const short8*)&As[buf][0][kbb][m_off + mi * 16 + (lane & 15)][0];
            if constexpr (ALO) al[mi] = *(const short8*)&As[buf][NTA - 1][kbb][m_off + mi * 16 + (lane & 15)][0];
        }
        #pragma unroll
        for (int ni = 0; ni < 4; ++ni) {
            wh[ni] = *(const short8*)&Ws[buf][0][kbb][n_off + ni * 16 + (lane & 15)][0];
            if constexpr (WLO) wl[ni] = *(const short8*)&Ws[buf][NTW - 1][kbb][n_off + ni * 16 + (lane & 15)][0];
        }
        #pragma unroll
        for (int mi = 0; mi < 4; ++mi) {
            #pragma unroll
            for (int ni = 0; ni < 4; ++ni) {
                acc[mi][ni] = __builtin_amdgcn_mfma_f32_16x16x32_bf16(ah[mi], wh[ni], acc[mi][ni], 0, 0, 0);
                if constexpr (WLO)
                    acc[mi][ni] = __builtin_amdgcn_mfma_f32_16x16x32_bf16(ah[mi], wl[ni], acc[mi][ni], 0, 0, 0);
                if constexpr (ALO)
                    acc[mi][ni] = __builtin_amdgcn_mfma_f32_16x16x32_bf16(al[mi], wh[ni], acc[mi][ni], 0, 0, 0);
            }
        }
    };

    stage(0, 0);
    #pragma unroll 2
    for (int t = 0; t < NT - 1; ++t) {
        const int cur = t & 1;
        stage(cur ^ 1, t + 1);  // prefetch next tile; stays in flight across the barrier
        // wait only for the PREVIOUS stage's CPW loads (counted, never 0 here)
        if constexpr (CPW == 8)      asm volatile("s_waitcnt vmcnt(8)" ::: "memory");
        else if constexpr (CPW == 6) asm volatile("s_waitcnt vmcnt(6)" ::: "memory");
        else                         asm volatile("s_waitcnt vmcnt(4)" ::: "memory");
        __builtin_amdgcn_s_barrier();
        compute(cur);
        __builtin_amdgcn_s_barrier();  // all waves done reading buf[cur] before overwrite
    }
    asm volatile("s_waitcnt vmcnt(0)" ::: "memory");
    __builtin_amdgcn_s_barrier();
    compute((NT - 1) & 1);

    // C/D layout: col = lane&15, row = (lane>>4)*4 + reg (m89-verified)
    const int rbase = m_blk + m_off + ((lane >> 4) << 2);
    const int cbase = n_blk + n_off + (lane & 15);
    #pragma unroll
    for (int mi = 0; mi < 4; ++mi) {
        #pragma unroll
        for (int r = 0; r < 4; ++r) {
            const int row = rbase + mi * 16 + r;
            if (row < M) {
                const float rd = rdeg[row];
                #pragma unroll
                for (int ni = 0; ni < 4; ++ni) {
                    const int col = cbase + ni * 16;
                    const float v = (acc[mi][ni][r] + bias[col]) * rd;
                    if constexpr (sizeof(HT) == 4) H[(size_t)row * DIM + col] = v;
                    else *(ushort_t*)&H[(size_t)row * DIM + col] = f2bf(v);
                }
            }
        }
    }
}

// ---------------------------------------------------------------------------
// v = ELU((H[i] + sum_{e>=0} H[e]) * rdeg[i])
// MODE 0: write v as bf16 hi (+ optional lo residual) -> next layer's A splits
// MODE 1: write final output, dtype per flags[0] (f32 or bf16)
// ---------------------------------------------------------------------------
template <typename HT>
__device__ __forceinline__ void addRow(const HT* H, int row, int d,
                                       float& a0, float& a1, float& a2, float& a3) {
    if constexpr (sizeof(HT) == 4) {
        const float4 v = *reinterpret_cast<const float4*>((const float*)H + (size_t)row * DIM + d);
        a0 += v.x; a1 += v.y; a2 += v.z; a3 += v.w;
    } else {
        const ushort4 v = *reinterpret_cast<const ushort4*>((const ushort_t*)H + (size_t)row * DIM + d);
        a0 += bf2f(v.x); a1 += bf2f(v.y); a2 += bf2f(v.z); a3 += bf2f(v.w);
    }
}

template <typename HT, int MODE>
__global__ __launch_bounds__(256)
void aggregate_gcn(const HT* __restrict__ H, const int* __restrict__ E,
                   const float* __restrict__ rdeg, const int* __restrict__ flags,
                   void* __restrict__ outA, ushort_t* __restrict__ outB, int n)
{
    const int node = blockIdx.x * 2 + (threadIdx.x >> 7);
    if (node >= n) return;
    const int t = threadIdx.x & 127;
    const int d = t << 2;
    int e0, e1, e2;
    if (flags[1]) { e0 = E[node * 6 + 0]; e1 = E[node * 6 + 2]; e2 = E[node * 6 + 4]; }
    else          { e0 = E[node * 3 + 0]; e1 = E[node * 3 + 1]; e2 = E[node * 3 + 2]; }
    const float rd = rdeg[node];

    float a0 = 0.f, a1 = 0.f, a2 = 0.f, a3 = 0.f;
    addRow(H, node, d, a0, a1, a2, a3);
    if (e0 >= 0) addRow(H, e0, d, a0, a1, a2, a3);
    if (e1 >= 0) addRow(H, e1, d, a0, a1, a2, a3);
    if (e2 >= 0) addRow(H, e2, d, a0, a1, a2, a3);

    a0 = elu_f(a0 * rd); a1 = elu_f(a1 * rd); a2 = elu_f(a2 * rd); a3 = elu_f(a3 * rd);

    const size_t base = (size_t)node * DIM + d;
    if constexpr (MODE == 0) {
        ushort4 h;
        h.x = f2bf(a0); h.y = f2bf(a1); h.z = f2bf(a2); h.w = f2bf(a3);
        *(ushort4*)((ushort_t*)outA + base) = h;
        if (outB) {
            ushort4 l;
            l.x = f2bf(a0 - bf2f(h.x)); l.y = f2bf(a1 - bf2f(h.y));
            l.z = f2bf(a2 - bf2f(h.z)); l.w = f2bf(a3 - bf2f(h.w));
            *(ushort4*)(outB + base) = l;
        }
    } else {
        if (flags[0]) {
            float4 o; o.x = a0; o.y = a1; o.z = a2; o.w = a3;
            *(float4*)((float*)outA + base) = o;
        } else {
            ushort4 o;
            o.x = f2bf(a0); o.y = f2bf(a1); o.z = f2bf(a2); o.w = f2bf(a3);
            *(ushort4*)((ushort_t*)outA + base) = o;
        }
    }
}

// ---------------------------------------------------------------------------
extern "C" void kernel_launch(void* const* d_in, const int* in_sizes, int n_in,
                              void* d_out, int out_size, void* d_ws, size_t ws_size,
                              hipStream_t stream) {
    const void* X  = d_in[0];
    const void* E  = d_in[1];
    const void* W1 = d_in[2];
    const void* b1 = d_in[3];
    const void* W2 = d_in[4];
    const void* b2 = d_in[5];
    const int* E32 = (const int*)E;

    const int M = in_sizes[0] / DIM;  // element counts are dtype-independent
    const long long NX = (long long)M * DIM;
    const long long NW = (long long)DIM * DIM;

    char* ws = (char*)d_ws;
    size_t off = 0;
    auto take = [&](size_t sz) { size_t o = off; off = (off + sz + 511) & ~(size_t)511; return o; };

    int*      flags = (int*)(ws + take(64));
    float*    rdeg  = (float*)(ws + take((size_t)M * 4));
    float*    b1f   = (float*)(ws + take(DIM * 4));
    float*    b2f   = (float*)(ws + take(DIM * 4));
    ushort_t* W1h   = (ushort_t*)(ws + take((size_t)NW * 2));
    ushort_t* W1l   = (ushort_t*)(ws + take((size_t)NW * 2));
    ushort_t* W2h   = (ushort_t*)(ws + take((size_t)NW * 2));
    ushort_t* W2l   = (ushort_t*)(ws + take((size_t)NW * 2));
    const size_t header = off;
    const size_t SX  = (size_t)NX * 2;
    const size_t SH4 = (size_t)NX * 4;
    const size_t SH2 = (size_t)NX * 2;

    // tier 0: full split (A hi/lo, W hi/lo, H f32) — error ~1e-4
    // tier 1: A hi only, W hi/lo, H f32           — error ~0.015 worst-case
    // tier 2: hi only, H bf16                     — last resort
    int tier;
    if      (ws_size >= header + 2 * SX + SH4 + 1024) tier = 0;
    else if (ws_size >= header + SX + SH4 + 1024)     tier = 1;
    else                                              tier = 2;

    ushort_t* Xh = (ushort_t*)(ws + take(SX));
    ushort_t* Xl = (tier == 0) ? (ushort_t*)(ws + take(SX)) : nullptr;
    void*     H  = ws + take(tier <= 1 ? SH4 : SH2);

    probe_kernel<<<1, 1, 0, stream>>>(X, E, flags);
    tof32_kernel<<<2, 256, 0, stream>>>(b1, b1f, DIM, flags);
    tof32_kernel<<<2, 256, 0, stream>>>(b2, b2f, DIM, flags);

    const int gW = (int)((NW / 8 + 255) / 256);
    const int gX = (int)((NX / 8 + 255) / 256);
    split_kernel<<<gW, 256, 0, stream>>>(W1, W1h, tier <= 1 ? W1l : nullptr, NW, flags);
    split_kernel<<<gW, 256, 0, stream>>>(W2, W2h, tier <= 1 ? W2l : nullptr, NW, flags);
    split_kernel<<<gX, 256, 0, stream>>>(X, Xh, Xl, NX, flags);
    degree_kernel<<<(M + 255) / 256, 256, 0, stream>>>(E32, rdeg, M, flags);

    const dim3 gG(DIM / BN, (M + BM - 1) / BM);
    const dim3 gA((M + 1) / 2);

    if (tier == 0) {
        gemm_gcn<true, true, float><<<gG, 256, 0, stream>>>(Xh, Xl, W1h, W1l, b1f, rdeg, (float*)H, M);
        aggregate_gcn<float, 0><<<gA, 256, 0, stream>>>((const float*)H, E32, rdeg, flags, Xh, Xl, M);
        gemm_gcn<true, true, float><<<gG, 256, 0, stream>>>(Xh, Xl, W2h, W2l, b2f, rdeg, (float*)H, M);
        aggregate_gcn<float, 1><<<gA, 256, 0, stream>>>((const float*)H, E32, rdeg, flags, d_out, nullptr, M);
    } else if (tier == 1) {
        gemm_gcn<false, true, float><<<gG, 256, 0, stream>>>(Xh, nullptr, W1h, W1l, b1f, rdeg, (float*)H, M);
        aggregate_gcn<float, 0><<<gA, 256, 0, stream>>>((const float*)H, E32, rdeg, flags, Xh, nullptr, M);
        gemm_gcn<false, true, float><<<gG, 256, 0, stream>>>(Xh, nullptr, W2h, W2l, b2f, rdeg, (float*)H, M);
        aggregate_gcn<float, 1><<<gA, 256, 0, stream>>>((const float*)H, E32, rdeg, flags, d_out, nullptr, M);
    } else {
        gemm_gcn<false, false, ushort_t><<<gG, 256, 0, stream>>>(Xh, nullptr, W1h, nullptr, b1f, rdeg, (ushort_t*)H, M);
        aggregate_gcn<ushort_t, 0><<<gA, 256, 0, stream>>>((const ushort_t*)H, E32, rdeg, flags, Xh, nullptr, M);
        gemm_gcn<false, false, ushort_t><<<gG, 256, 0, stream>>>(Xh, nullptr, W2h, nullptr, b2f, rdeg, (ushort_t*)H, M);
        aggregate_gcn<ushort_t, 1><<<gA, 256, 0, stream>>>((const ushort_t*)H, E32, rdeg, flags, d_out, nullptr, M);
    }
}

// Round 2
// 1236.307 us; speedup vs baseline: 1.0307x; 1.0067x over previous
//
#include <hip/hip_runtime.h>
#include <cstdint>
#include <cstddef>

#define DIM 512
#define BM 256
#define BN 256
#define BK 32

typedef unsigned short ushort_t;
typedef __attribute__((ext_vector_type(8))) short short8;   // 8 bf16 MFMA frag
typedef __attribute__((ext_vector_type(4))) float floatx4;  // MFMA accumulator
typedef __attribute__((address_space(3))) void lds_void;
typedef __attribute__((address_space(1))) void gbl_void;

__device__ __forceinline__ float bf2f(ushort_t s) {
    unsigned u = ((unsigned)s) << 16;
    float f;
    __builtin_memcpy(&f, &u, 4);
    return f;
}
__device__ __forceinline__ ushort_t f2bf(float f) {  // round-to-nearest-even
    unsigned u;
    __builtin_memcpy(&u, &f, 4);
    u = u + 0x7FFFu + ((u >> 16) & 1u);
    return (ushort_t)(u >> 16);
}
__device__ __forceinline__ float elu_f(float x) { return x > 0.0f ? x : __expf(x) - 1.0f; }

// ---------------------------------------------------------------------------
// Dtype probe. flags[0]=1 if x is float32 (else bf16). flags[1]=1 if edges are
// int64 (else int32). f32 data read as bf16: even ushorts are mid-mantissa
// bits -> random exponent fields -> "crazy" bf16 values ~75% of the time.
// int64 edges in [-1,N): odd int32 words are sign-extensions (0 or -1) always.
// ---------------------------------------------------------------------------
__global__ void probe_kernel(const void* __restrict__ x, const void* __restrict__ e,
                             int* __restrict__ flags) {
    if (threadIdx.x != 0 || blockIdx.x != 0) return;
    const ushort_t* u = (const ushort_t*)x;
    int crazy = 0;
    for (int j = 0; j < 512; ++j) {
        const ushort_t s = u[2 * j];
        const int ex = (s >> 7) & 0xFF;
        const bool nonzero = (s & 0x7FFF) != 0;
        if (ex >= 160 || (ex < 96 && nonzero)) crazy++;
    }
    const int* w = (const int*)e;
    int se = 0;
    for (int j = 0; j < 64; ++j) {
        const int v = w[2 * j + 1];
        if (v == 0 || v == -1) se++;
    }
    flags[0] = (crazy > 64) ? 1 : 0;
    flags[1] = (se >= 60) ? 1 : 0;
}

// bias -> f32, either source dtype
__global__ void tof32_kernel(const void* __restrict__ src, float* __restrict__ dst,
                             int n, const int* __restrict__ flags) {
    const int i = blockIdx.x * blockDim.x + threadIdx.x;
    if (i < n) dst[i] = flags[0] ? ((const float*)src)[i] : bf2f(((const ushort_t*)src)[i]);
}

// ---------------------------------------------------------------------------
// src (f32 or bf16 per flag) -> hi bf16 (+ optional lo bf16 residual).
// 8 elements per thread, n must be a multiple of 8.
// ---------------------------------------------------------------------------
__global__ __launch_bounds__(256)
void split_kernel(const void* __restrict__ src, ushort_t* __restrict__ hi,
                  ushort_t* __restrict__ lo, long long n, const int* __restrict__ flags) {
    const long long i = ((long long)blockIdx.x * blockDim.x + threadIdx.x) * 8;
    if (i >= n) return;
    const bool isf32 = flags[0] != 0;
    float v[8];
    if (isf32) {
        const float* s = (const float*)src + i;
        const float4 f0 = *(const float4*)s;
        const float4 f1 = *(const float4*)(s + 4);
        v[0] = f0.x; v[1] = f0.y; v[2] = f0.z; v[3] = f0.w;
        v[4] = f1.x; v[5] = f1.y; v[6] = f1.z; v[7] = f1.w;
    } else {
        const ushort_t* s = (const ushort_t*)src + i;
        const ushort4 u0 = *(const ushort4*)s;
        const ushort4 u1 = *(const ushort4*)(s + 4);
        v[0] = bf2f(u0.x); v[1] = bf2f(u0.y); v[2] = bf2f(u0.z); v[3] = bf2f(u0.w);
        v[4] = bf2f(u1.x); v[5] = bf2f(u1.y); v[6] = bf2f(u1.z); v[7] = bf2f(u1.w);
    }
    ushort_t h[8];
    #pragma unroll
    for (int j = 0; j < 8; ++j) h[j] = f2bf(v[j]);
    ushort4 a, b;
    a.x = h[0]; a.y = h[1]; a.z = h[2]; a.w = h[3];
    b.x = h[4]; b.y = h[5]; b.z = h[6]; b.w = h[7];
    *(ushort4*)(hi + i) = a;
    *(ushort4*)(hi + i + 4) = b;
    if (lo) {
        ushort4 la, lb;
        la.x = isf32 ? f2bf(v[0] - bf2f(h[0])) : 0;
        la.y = isf32 ? f2bf(v[1] - bf2f(h[1])) : 0;
        la.z = isf32 ? f2bf(v[2] - bf2f(h[2])) : 0;
        la.w = isf32 ? f2bf(v[3] - bf2f(h[3])) : 0;
        lb.x = isf32 ? f2bf(v[4] - bf2f(h[4])) : 0;
        lb.y = isf32 ? f2bf(v[5] - bf2f(h[5])) : 0;
        lb.z = isf32 ? f2bf(v[6] - bf2f(h[6])) : 0;
        lb.w = isf32 ? f2bf(v[7] - bf2f(h[7])) : 0;
        *(ushort4*)(lo + i) = la;
        *(ushort4*)(lo + i + 4) = lb;
    }
}

__global__ void degree_kernel(const int* __restrict__ E, float* __restrict__ rdeg,
                              int n, const int* __restrict__ flags) {
    const int i = blockIdx.x * blockDim.x + threadIdx.x;
    if (i >= n) return;
    int e0, e1, e2;
    if (flags[1]) { e0 = E[i * 6 + 0]; e1 = E[i * 6 + 2]; e2 = E[i * 6 + 4]; }
    else          { e0 = E[i * 3 + 0]; e1 = E[i * 3 + 1]; e2 = E[i * 3 + 2]; }
    const int dg = 1 + (e0 >= 0) + (e1 >= 0) + (e2 >= 0);
    rdeg[i] = 1.0f / sqrtf((float)dg);
}

// ---------------------------------------------------------------------------
// H[row][col] = (sum_k A[row][k]*W[col][k] + bias[col]) * rdeg[row]
// with A ~ Ahi + Alo, W ~ Whi + Wlo (bf16 splits of f32), dropping lo*lo.
//
// v3: staged-traffic analysis — both prior rounds delivered (BM+BN)*K*4B per
// block through LDS at a constant ~5.1 TB/s regardless of HBM mix, so the
// GEMM is cache->LDS delivery-bound. 256x256 tile halves staged bytes per
// FLOP (810 MB vs 1.6 GB per GEMM) and doubles per-iteration MFMA for
// latency hiding. 8 waves (2M x 4N of 128x64 each), BK=32, double-buffered
// LDS (128 KB tier0, 1 block/CU), counted vmcnt pipeline, bijective XCD
// swizzle. LDS layout [buf][tile][kb][row][8]: global_load_lds wave-uniform
// base + lane*16, measured conflict-free ds_read_b128.
// ---------------------------------------------------------------------------
template <bool ALO, bool WLO, typename HT>
__global__ __launch_bounds__(512, 2)
void gemm_gcn(const ushort_t* __restrict__ Ahi, const ushort_t* __restrict__ Alo,
              const ushort_t* __restrict__ Whi, const ushort_t* __restrict__ Wlo,
              const float* __restrict__ bias, const float* __restrict__ rdeg,
              HT* __restrict__ H, int M)
{
    constexpr int NTA = ALO ? 2 : 1;
    constexpr int NTW = WLO ? 2 : 1;
    constexpr int CPW = 2 * (NTA + NTW);  // 1KB chunks per wave per stage (16*(NTA+NTW)/8)
    constexpr int NXB = DIM / BN;         // 2 N-blocks
    constexpr int NT  = DIM / BK;         // 16 K-tiles
    __shared__ __align__(16) ushort_t As[2][NTA][BK / 8][BM][8];  // 16KB per split per buf
    __shared__ __align__(16) ushort_t Ws[2][NTW][BK / 8][BN][8];

    const int tid  = threadIdx.x;
    const int wave = tid >> 6;
    const int lane = tid & 63;

    // bijective XCD swizzle (m204): consecutive original ids (which share an
    // A-panel, since N is the fast grid dim) map to the same XCD.
    const int nwg = NXB * gridDim.y;
    const int bid = blockIdx.y * NXB + blockIdx.x;
    const int q = nwg >> 3, rm = nwg & 7;
    const int xcd = bid & 7, lin = bid >> 3;
    const int swz = (xcd < rm ? xcd * (q + 1) : rm * (q + 1) + (xcd - rm) * q) + lin;
    const int n_blk = (swz & (NXB - 1)) * BN;
    const int m_blk = (swz / NXB) * BM;

    const int m_off = (wave & 1) * 128;  // 2 wave-rows of 128
    const int n_off = (wave >> 1) * 64;  // 4 wave-cols of 64

    floatx4 acc[8][4] = {};

    auto stage = [&](int buf, int t) {
        const int k0 = t * BK;
        #pragma unroll
        for (int i = 0; i < CPW; ++i) {
            const int cc   = wave + i * 8;   // chunk id in [0, 16*(NTA+NTW))
            const int tile = cc >> 4;        // 16 chunks per split-tile
            const int c    = cc & 15;
            const int kb   = c >> 2;         // 4 K-slices of 8
            const int rh   = (c & 3) * 64;   // 4 row-groups of 64
            if (tile < NTA) {
                int r = m_blk + rh + lane;
                r = r < M ? r : M - 1;  // clamp; rows >= M never stored
                const ushort_t* src = (tile == 0 ? Ahi : Alo) + (size_t)r * DIM + k0 + kb * 8;
                __builtin_amdgcn_global_load_lds((gbl_void*)src, (lds_void*)&As[buf][tile][kb][rh][0], 16, 0, 0);
            } else {
                const int tt = tile - NTA;
                const int r = n_blk + rh + lane;  // < 512 always
                const ushort_t* src = (tt == 0 ? Whi : Wlo) + (size_t)r * DIM + k0 + kb * 8;
                __builtin_amdgcn_global_load_lds((gbl_void*)src, (lds_void*)&Ws[buf][tt][kb][rh][0], 16, 0, 0);
            }
        }
    };

    auto compute = [&](int buf) {
        const int kbb = lane >> 4;  // lane quarter picks 8-wide K slice of K=32
        short8 wh[4], wl[4];
        #pragma unroll
        for (int ni = 0; ni < 4; ++ni) {
            wh[ni] = *(const short8*)&Ws[buf][0][kbb][n_off + ni * 16 + (lane & 15)][0];
            if constexpr (WLO) wl[ni] = *(const short8*)&Ws[buf][NTW - 1][kbb][n_off + ni * 16 + (lane & 15)][0];
        }
        #pragma unroll
        for (int mi = 0; mi < 8; ++mi) {
            short8 ah = *(const short8*)&As[buf][0][kbb][m_off + mi * 16 + (lane & 15)][0];
            short8 al;
            if constexpr (ALO) al = *(const short8*)&As[buf][NTA - 1][kbb][m_off + mi * 16 + (lane & 15)][0];
            #pragma unroll
            for (int ni = 0; ni < 4; ++ni) {
                acc[mi][ni] = __builtin_amdgcn_mfma_f32_16x16x32_bf16(ah, wh[ni], acc[mi][ni], 0, 0, 0);
                if constexpr (WLO)
                    acc[mi][ni] = __builtin_amdgcn_mfma_f32_16x16x32_bf16(ah, wl[ni], acc[mi][ni], 0, 0, 0);
                if constexpr (ALO)
                    acc[mi][ni] = __builtin_amdgcn_mfma_f32_16x16x32_bf16(al, wh[ni], acc[mi][ni], 0, 0, 0);
            }
        }
    };

    stage(0, 0);
    #pragma unroll 2
    for (int t = 0; t < NT - 1; ++t) {
        const int cur = t & 1;
        stage(cur ^ 1, t + 1);  // prefetch next tile; stays in flight across the barrier
        // wait only for the PREVIOUS stage's CPW loads (counted, never 0 here)
        if constexpr (CPW == 8)      asm volatile("s_waitcnt vmcnt(8)" ::: "memory");
        else if constexpr (CPW == 6) asm volatile("s_waitcnt vmcnt(6)" ::: "memory");
        else                         asm volatile("s_waitcnt vmcnt(4)" ::: "memory");
        __builtin_amdgcn_s_barrier();
        compute(cur);
        __builtin_amdgcn_s_barrier();  // all waves done reading buf[cur] before overwrite
    }
    asm volatile("s_waitcnt vmcnt(0)" ::: "memory");
    __builtin_amdgcn_s_barrier();
    compute((NT - 1) & 1);

    // C/D layout: col = lane&15, row = (lane>>4)*4 + reg (m89-verified)
    const int rbase = m_blk + m_off + ((lane >> 4) << 2);
    const int cbase = n_blk + n_off + (lane & 15);
    #pragma unroll
    for (int mi = 0; mi < 8; ++mi) {
        #pragma unroll
        for (int r = 0; r < 4; ++r) {
            const int row = rbase + mi * 16 + r;
            if (row < M) {
                const float rd = rdeg[row];
                #pragma unroll
                for (int ni = 0; ni < 4; ++ni) {
                    const int col = cbase + ni * 16;
                    const float v = (acc[mi][ni][r] + bias[col]) * rd;
                    if constexpr (sizeof(HT) == 4) H[(size_t)row * DIM + col] = v;
                    else *(ushort_t*)&H[(size_t)row * DIM + col] = f2bf(v);
                }
            }
        }
    }
}

// ---------------------------------------------------------------------------
// v = ELU((H[i] + sum_{e>=0} H[e]) * rdeg[i])
// MODE 0: write v as bf16 hi (+ optional lo residual) -> next layer's A splits
// MODE 1: write final output, dtype per flags[0] (f32 or bf16)
// ---------------------------------------------------------------------------
template <typename HT>
__device__ __forceinline__ void addRow(const HT* H, int row, int d,
                                       float& a0, float& a1, float& a2, float& a3) {
    if constexpr (sizeof(HT) == 4) {
        const float4 v = *reinterpret_cast<const float4*>((const float*)H + (size_t)row * DIM + d);
        a0 += v.x; a1 += v.y; a2 += v.z; a3 += v.w;
    } else {
        const ushort4 v = *reinterpret_cast<const ushort4*>((const ushort_t*)H + (size_t)row * DIM + d);
        a0 += bf2f(v.x); a1 += bf2f(v.y); a2 += bf2f(v.z); a3 += bf2f(v.w);
    }
}

template <typename HT, int MODE>
__global__ __launch_bounds__(256)
void aggregate_gcn(const HT* __restrict__ H, const int* __restrict__ E,
                   const float* __restrict__ rdeg, const int* __restrict__ flags,
                   void* __restrict__ outA, ushort_t* __restrict__ outB, int n)
{
    const int node = blockIdx.x * 2 + (threadIdx.x >> 7);
    if (node >= n) return;
    const int t = threadIdx.x & 127;
    const int d = t << 2;
    int e0, e1, e2;
    if (flags[1]) { e0 = E[node * 6 + 0]; e1 = E[node * 6 + 2]; e2 = E[node * 6 + 4]; }
    else          { e0 = E[node * 3 + 0]; e1 = E[node * 3 + 1]; e2 = E[node * 3 + 2]; }
    const float rd = rdeg[node];

    float a0 = 0.f, a1 = 0.f, a2 = 0.f, a3 = 0.f;
    addRow(H, node, d, a0, a1, a2, a3);
    if (e0 >= 0) addRow(H, e0, d, a0, a1, a2, a3);
    if (e1 >= 0) addRow(H, e1, d, a0, a1, a2, a3);
    if (e2 >= 0) addRow(H, e2, d, a0, a1, a2, a3);

    a0 = elu_f(a0 * rd); a1 = elu_f(a1 * rd); a2 = elu_f(a2 * rd); a3 = elu_f(a3 * rd);

    const size_t base = (size_t)node * DIM + d;
    if constexpr (MODE == 0) {
        ushort4 h;
        h.x = f2bf(a0); h.y = f2bf(a1); h.z = f2bf(a2); h.w = f2bf(a3);
        *(ushort4*)((ushort_t*)outA + base) = h;
        if (outB) {
            ushort4 l;
            l.x = f2bf(a0 - bf2f(h.x)); l.y = f2bf(a1 - bf2f(h.y));
            l.z = f2bf(a2 - bf2f(h.z)); l.w = f2bf(a3 - bf2f(h.w));
            *(ushort4*)(outB + base) = l;
        }
    } else {
        if (flags[0]) {
            float4 o; o.x = a0; o.y = a1; o.z = a2; o.w = a3;
            *(float4*)((float*)outA + base) = o;
        } else {
            ushort4 o;
            o.x = f2bf(a0); o.y = f2bf(a1); o.z = f2bf(a2); o.w = f2bf(a3);
            *(ushort4*)((ushort_t*)outA + base) = o;
        }
    }
}

// ---------------------------------------------------------------------------
extern "C" void kernel_launch(void* const* d_in, const int* in_sizes, int n_in,
                              void* d_out, int out_size, void* d_ws, size_t ws_size,
                              hipStream_t stream) {
    const void* X  = d_in[0];
    const void* E  = d_in[1];
    const void* W1 = d_in[2];
    const void* b1 = d_in[3];
    const void* W2 = d_in[4];
    const void* b2 = d_in[5];
    const int* E32 = (const int*)E;

    const int M = in_sizes[0] / DIM;  // element counts are dtype-independent
    const long long NX = (long long)M * DIM;
    const long long NW = (long long)DIM * DIM;

    char* ws = (char*)d_ws;
    size_t off = 0;
    auto take = [&](size_t sz) { size_t o = off; off = (off + sz + 511) & ~(size_t)511; return o; };

    int*      flags = (int*)(ws + take(64));
    float*    rdeg  = (float*)(ws + take((size_t)M * 4));
    float*    b1f   = (float*)(ws + take(DIM * 4));
    float*    b2f   = (float*)(ws + take(DIM * 4));
    ushort_t* W1h   = (ushort_t*)(ws + take((size_t)NW * 2));
    ushort_t* W1l   = (ushort_t*)(ws + take((size_t)NW * 2));
    ushort_t* W2h   = (ushort_t*)(ws + take((size_t)NW * 2));
    ushort_t* W2l   = (ushort_t*)(ws + take((size_t)NW * 2));
    const size_t header = off;
    const size_t SX  = (size_t)NX * 2;
    const size_t SH4 = (size_t)NX * 4;
    const size_t SH2 = (size_t)NX * 2;

    // tier 0: full split (A hi/lo, W hi/lo, H f32) — error ~1e-4
    // tier 1: A hi only, W hi/lo, H f32           — error ~0.015 worst-case
    // tier 2: hi only, H bf16                     — last resort
    int tier;
    if      (ws_size >= header + 2 * SX + SH4 + 1024) tier = 0;
    else if (ws_size >= header + SX + SH4 + 1024)     tier = 1;
    else                                              tier = 2;

    ushort_t* Xh = (ushort_t*)(ws + take(SX));
    ushort_t* Xl = (tier == 0) ? (ushort_t*)(ws + take(SX)) : nullptr;
    void*     H  = ws + take(tier <= 1 ? SH4 : SH2);

    probe_kernel<<<1, 1, 0, stream>>>(X, E, flags);
    tof32_kernel<<<2, 256, 0, stream>>>(b1, b1f, DIM, flags);
    tof32_kernel<<<2, 256, 0, stream>>>(b2, b2f, DIM, flags);

    const int gW = (int)((NW / 8 + 255) / 256);
    const int gX = (int)((NX / 8 + 255) / 256);
    split_kernel<<<gW, 256, 0, stream>>>(W1, W1h, tier <= 1 ? W1l : nullptr, NW, flags);
    split_kernel<<<gW, 256, 0, stream>>>(W2, W2h, tier <= 1 ? W2l : nullptr, NW, flags);
    split_kernel<<<gX, 256, 0, stream>>>(X, Xh, Xl, NX, flags);
    degree_kernel<<<(M + 255) / 256, 256, 0, stream>>>(E32, rdeg, M, flags);

    const dim3 gG(DIM / BN, (M + BM - 1) / BM);
    const dim3 gA((M + 1) / 2);

    if (tier == 0) {
        gemm_gcn<true, true, float><<<gG, 512, 0, stream>>>(Xh, Xl, W1h, W1l, b1f, rdeg, (float*)H, M);
        aggregate_gcn<float, 0><<<gA, 256, 0, stream>>>((const float*)H, E32, rdeg, flags, Xh, Xl, M);
        gemm_gcn<true, true, float><<<gG, 512, 0, stream>>>(Xh, Xl, W2h, W2l, b2f, rdeg, (float*)H, M);
        aggregate_gcn<float, 1><<<gA, 256, 0, stream>>>((const float*)H, E32, rdeg, flags, d_out, nullptr, M);
    } else if (tier == 1) {
        gemm_gcn<false, true, float><<<gG, 512, 0, stream>>>(Xh, nullptr, W1h, W1l, b1f, rdeg, (float*)H, M);
        aggregate_gcn<float, 0><<<gA, 256, 0, stream>>>((const float*)H, E32, rdeg, flags, Xh, nullptr, M);
        gemm_gcn<false, true, float><<<gG, 512, 0, stream>>>(Xh, nullptr, W2h, W2l, b2f, rdeg, (float*)H, M);
        aggregate_gcn<float, 1><<<gA, 256, 0, stream>>>((const float*)H, E32, rdeg, flags, d_out, nullptr, M);
    } else {
        gemm_gcn<false, false, ushort_t><<<gG, 512, 0, stream>>>(Xh, nullptr, W1h, nullptr, b1f, rdeg, (ushort_t*)H, M);
        aggregate_gcn<ushort_t, 0><<<gA, 256, 0, stream>>>((const ushort_t*)H, E32, rdeg, flags, Xh, nullptr, M);
        gemm_gcn<false, false, ushort_t><<<gG, 512, 0, stream>>>(Xh, nullptr, W2h, nullptr, b2f, rdeg, (ushort_t*)H, M);
        aggregate_gcn<ushort_t, 1><<<gA, 256, 0, stream>>>((const ushort_t*)H, E32, rdeg, flags, d_out, nullptr, M);
    }
}